// Round 1
// baseline (348.916 us; speedup 1.0000x reference)
//
#include <hip/hip_runtime.h>
#include <hip/hip_bf16.h>
#include <math.h>

#define NC     1000000   // num classes
#define DIM    64
#define BATCH  4096
#define NS     1024      // num sampled

// ws layout (floats):
//   [0 .. 64*1024)        sw_t[d][j] = item_emb[d, sampled[j]]  (transposed gather)
//   [WS_SLQ .. +1024)     samp_log_q[j]
//   [WS_TLOG .. +4096)    true_logit[b]  (dot - true_log_q)
#define WS_SWT  0
#define WS_SLQ  (DIM * NS)
#define WS_TLOG (WS_SLQ + NS)

// prep grid decomposition (256-thread blocks):
//   blocks [0, 256):    sampled gather, block = (d = blk>>2, j-quarter = blk&3)
//   blocks [256, 260):  samp_log_q, 4 x 256 = 1024 lanes
//   blocks [260, 276):  true logits, 16 x 256 = 4096 lanes (lane = batch row)
#define PREP_GATHER_BLOCKS 256
#define PREP_SLQ_BASE      256
#define PREP_TL_BASE       260
#define PREP_BLOCKS        276

// Replicate the numpy reference's fp32 log-uniform prob BIT-FOR-BIT.
// The reference computes log(c+2)-log(c+1) in float32, where the true gap
// (~1/c ~ 1e-6 for c~1e6) is ~1 ulp of log(c)~13.8 -> the gap is quantized
// to integer multiples of ulp (error up to +-log2 in log_q). We must
// reproduce that quantization, not fix it: compute each log in double
// (correctly rounded), round to fp32, subtract in fp32 (exact, Sterbenz),
// finish in double (well-conditioned; matches NEP-50 float64 promotion).
__device__ __forceinline__ float log_q(int c) {
  float l2 = (float)log((double)c + 2.0);
  float l1 = (float)log((double)c + 1.0);
  float diff = l2 - l1;
  double p = (double)diff / log((double)NC + 1.0);
  return (float)log((double)NS * p);
}

// Restructured prep: lane = column/row index (TLB-local random gathers,
// coalesced stores); d is the block/loop dimension.
__global__ __launch_bounds__(256) void prep_kernel(
    const float* __restrict__ item,   // [DIM, NC]
    const float* __restrict__ user,   // [DIM, BATCH]
    const int* __restrict__ label,    // [BATCH]
    const int* __restrict__ sampled,  // [NS]
    float* __restrict__ ws) {
  const int blk = blockIdx.x;
  const int t = threadIdx.x;

  if (blk < PREP_GATHER_BLOCKS) {
    // sw_t[d][j] = item[d, sampled[j]]
    // lane = j (coalesced sampled read + coalesced ws store); the 64 random
    // item addresses per wave all fall inside one 4 MB d-slice (TLB-local).
    const int d = blk >> 2;
    const int j = ((blk & 3) << 8) + t;
    const int c = sampled[j];
    ws[WS_SWT + d * NS + j] = item[(size_t)d * NC + c];
  } else if (blk < PREP_TL_BASE) {
    // samp_log_q[j], one lane per j (fp64 logs fully parallel)
    const int j = ((blk - PREP_SLQ_BASE) << 8) + t;
    ws[WS_SLQ + j] = log_q(sampled[j]);
  } else {
    // true_logit[b] = sum_d item[d, label[b]] * user[d, b] - log_q(label[b])
    // lane = b: user reads coalesced (256B/wave per d); item gathers are
    // random 4B but confined to one 4 MB slice per d. Full unroll gives the
    // scheduler deep load ILP (addresses all computable up front).
    const int b = ((blk - PREP_TL_BASE) << 8) + t;
    const int c = label[b];
    const float* ip = item + c;
    const float* up = user + b;
    float acc = 0.f;
    #pragma unroll
    for (int d = 0; d < DIM; ++d)
      acc = fmaf(ip[(size_t)d * NC], up[d * BATCH], acc);
    ws[WS_TLOG + b] = acc - log_q(c);
  }
}

// 512 blocks x 256 threads; block handles 8 batch rows, thread handles 4 consecutive j.
__global__ __launch_bounds__(256) void main_kernel(
    const int* __restrict__ label,
    const int* __restrict__ sampled,
    const float* __restrict__ user,
    const float* __restrict__ ws,
    float* __restrict__ out) {
  __shared__ float u_lds[8 * DIM];   // u[r][d]
  __shared__ float red_m[4][8];
  __shared__ float red_l[4][8];

  const int t = threadIdx.x;
  const int r0 = blockIdx.x * 8;

  // stage user columns for the 8 rows
  for (int i = t; i < 8 * DIM; i += 256) {
    int r = i & 7;
    int d = i >> 3;
    u_lds[r * DIM + d] = user[d * BATCH + r0 + r];
  }
  __syncthreads();

  float acc[8][4];
  #pragma unroll
  for (int r = 0; r < 8; ++r)
    #pragma unroll
    for (int jj = 0; jj < 4; ++jj) acc[r][jj] = 0.f;

  // acc[r][jj] = sum_d u[r][d] * sw_t[d][t*4+jj]   (coalesced float4 reads of sw_t)
  const float* sp = ws + WS_SWT + t * 4;
  #pragma unroll
  for (int d4 = 0; d4 < 16; ++d4) {
    const float4 s0 = *(const float4*)(sp + (d4 * 4 + 0) * NS);
    const float4 s1 = *(const float4*)(sp + (d4 * 4 + 1) * NS);
    const float4 s2 = *(const float4*)(sp + (d4 * 4 + 2) * NS);
    const float4 s3 = *(const float4*)(sp + (d4 * 4 + 3) * NS);
    #pragma unroll
    for (int r = 0; r < 8; ++r) {
      const float4 u4 = *(const float4*)(&u_lds[r * DIM + d4 * 4]);  // broadcast read
      acc[r][0] = fmaf(u4.w, s3.x, fmaf(u4.z, s2.x, fmaf(u4.y, s1.x, fmaf(u4.x, s0.x, acc[r][0]))));
      acc[r][1] = fmaf(u4.w, s3.y, fmaf(u4.z, s2.y, fmaf(u4.y, s1.y, fmaf(u4.x, s0.y, acc[r][1]))));
      acc[r][2] = fmaf(u4.w, s3.z, fmaf(u4.z, s2.z, fmaf(u4.y, s1.z, fmaf(u4.x, s0.z, acc[r][2]))));
      acc[r][3] = fmaf(u4.w, s3.w, fmaf(u4.z, s2.w, fmaf(u4.y, s1.w, fmaf(u4.x, s0.w, acc[r][3]))));
    }
  }

  int labv[8];
  #pragma unroll
  for (int r = 0; r < 8; ++r) labv[r] = label[r0 + r];

  const float4 sq = *(const float4*)(ws + WS_SLQ + t * 4);
  const int4  sid = *(const int4*)(sampled + t * 4);

  // per-thread online softmax over its 4 logits (hit-masked)
  float m[8], l[8];
  #pragma unroll
  for (int r = 0; r < 8; ++r) {
    float lg0 = acc[r][0] - sq.x; if (sid.x == labv[r]) lg0 -= 1e9f;
    float lg1 = acc[r][1] - sq.y; if (sid.y == labv[r]) lg1 -= 1e9f;
    float lg2 = acc[r][2] - sq.z; if (sid.z == labv[r]) lg2 -= 1e9f;
    float lg3 = acc[r][3] - sq.w; if (sid.w == labv[r]) lg3 -= 1e9f;
    float mm = fmaxf(fmaxf(lg0, lg1), fmaxf(lg2, lg3));
    l[r] = __expf(lg0 - mm) + __expf(lg1 - mm) + __expf(lg2 - mm) + __expf(lg3 - mm);
    m[r] = mm;
  }

  // 64-lane butterfly combine (all lanes of a wave hold the same 8 rows)
  #pragma unroll
  for (int off = 1; off < 64; off <<= 1) {
    #pragma unroll
    for (int r = 0; r < 8; ++r) {
      float om = __shfl_xor(m[r], off, 64);
      float ol = __shfl_xor(l[r], off, 64);
      float nm = fmaxf(m[r], om);
      l[r] = l[r] * __expf(m[r] - nm) + ol * __expf(om - nm);
      m[r] = nm;
    }
  }

  const int wave = t >> 6;
  if ((t & 63) == 0) {
    #pragma unroll
    for (int r = 0; r < 8; ++r) { red_m[wave][r] = m[r]; red_l[wave][r] = l[r]; }
  }
  __syncthreads();

  if (t < 8) {
    const int r = t;
    float mm = red_m[0][r], ll = red_l[0][r];
    #pragma unroll
    for (int w = 1; w < 4; ++w) {
      float om = red_m[w][r], ol = red_l[w][r];
      float nm = fmaxf(mm, om);
      ll = ll * __expf(mm - nm) + ol * __expf(om - nm);
      mm = nm;
    }
    // loss = logsumexp(true_logit, sampled...) - true_logit
    const float tl = ws[WS_TLOG + r0 + r];
    const float M = fmaxf(mm, tl);
    const float loss = logf(ll * __expf(mm - M) + __expf(tl - M)) + (M - tl);
    out[r0 + r] = loss;
  }
}

extern "C" void kernel_launch(void* const* d_in, const int* in_sizes, int n_in,
                              void* d_out, int out_size, void* d_ws, size_t ws_size,
                              hipStream_t stream) {
  const float* item  = (const float*)d_in[0];
  const float* user  = (const float*)d_in[1];
  const int* label   = (const int*)d_in[2];
  const int* sampled = (const int*)d_in[3];
  float* ws = (float*)d_ws;
  float* out = (float*)d_out;

  prep_kernel<<<PREP_BLOCKS, 256, 0, stream>>>(item, user, label, sampled, ws);
  main_kernel<<<BATCH / 8, 256, 0, stream>>>(label, sampled, user, ws, out);
}

// Round 2
// 315.637 us; speedup vs baseline: 1.1054x; 1.1054x over previous
//
#include <hip/hip_runtime.h>
#include <hip/hip_bf16.h>
#include <math.h>

#define NC     1000000   // num classes
#define DIM    64
#define BATCH  4096
#define NS     1024      // num sampled

// ws layout (floats):
//   [0 .. 64*1024)        sw_t[d][j] = item_emb[d, sampled[j]]  (transposed gather)
//   [WS_SLQ .. +1024)     samp_log_q[j]
//   [WS_TLOG .. +4096)    true_logit[b]  (dot - true_log_q)
#define WS_SWT  0
#define WS_SLQ  (DIM * NS)
#define WS_TLOG (WS_SLQ + NS)

// Replicate the numpy reference's fp32 log-uniform prob BIT-FOR-BIT.
// The reference computes log(c+2)-log(c+1) in float32, where the true gap
// (~1/c ~ 1e-6 for c~1e6) is ~1 ulp of log(c)~13.8 -> the gap is quantized
// to integer multiples of ulp (error up to +-log2 in log_q). We must
// reproduce that quantization, not fix it: compute each log in double
// (correctly rounded), round to fp32, subtract in fp32 (exact, Sterbenz),
// finish in double (well-conditioned; matches NEP-50 float64 promotion).
__device__ __forceinline__ float log_q(int c) {
  float l2 = (float)log((double)c + 2.0);
  float l1 = (float)log((double)c + 1.0);
  float diff = l2 - l1;
  double p = (double)diff / log((double)NC + 1.0);
  return (float)log((double)NS * p);
}

// NOTE (round-1 post-mortem): a "TLB-friendly" restructure of this kernel
// (lane = column, 276 blocks total, true-logit on 16 blocks x 256 threads)
// REGRESSED +32 us: the true-logit phase lost full-chip TLP (16 of 256 CUs
// active, 64 serial random gathers per thread at ~900cy HBM latency).
// This 5120-block layout keeps every CU busy; measured as part of the
// 316.5 us best (fills 2x155 us + ~6 us of kernel work).
__global__ __launch_bounds__(64) void prep_kernel(
    const float* __restrict__ item,   // [DIM, NC]
    const float* __restrict__ user,   // [DIM, BATCH]
    const int* __restrict__ label,    // [BATCH]
    const int* __restrict__ sampled,  // [NS]
    float* __restrict__ ws) {
  const int blk = blockIdx.x;
  const int d = threadIdx.x;   // 0..63 = one wave
  if (blk < NS) {
    const int j = blk;
    const int c = sampled[j];
    ws[WS_SWT + d * NS + j] = item[(size_t)d * NC + c];
    if (d == 0) ws[WS_SLQ + j] = log_q(c);
  } else {
    const int b = blk - NS;
    const int c = label[b];
    float p = item[(size_t)d * NC + c] * user[d * BATCH + b];
    #pragma unroll
    for (int off = 32; off > 0; off >>= 1) p += __shfl_down(p, off, 64);
    if (d == 0) ws[WS_TLOG + b] = p - log_q(c);
  }
}

// 512 blocks x 256 threads; block handles 8 batch rows, thread handles 4 consecutive j.
__global__ __launch_bounds__(256) void main_kernel(
    const int* __restrict__ label,
    const int* __restrict__ sampled,
    const float* __restrict__ user,
    const float* __restrict__ ws,
    float* __restrict__ out) {
  __shared__ float u_lds[8 * DIM];   // u[r][d]
  __shared__ float red_m[4][8];
  __shared__ float red_l[4][8];

  const int t = threadIdx.x;
  const int r0 = blockIdx.x * 8;

  // stage user columns for the 8 rows
  for (int i = t; i < 8 * DIM; i += 256) {
    int r = i & 7;
    int d = i >> 3;
    u_lds[r * DIM + d] = user[d * BATCH + r0 + r];
  }
  __syncthreads();

  float acc[8][4];
  #pragma unroll
  for (int r = 0; r < 8; ++r)
    #pragma unroll
    for (int jj = 0; jj < 4; ++jj) acc[r][jj] = 0.f;

  // acc[r][jj] = sum_d u[r][d] * sw_t[d][t*4+jj]   (coalesced float4 reads of sw_t)
  const float* sp = ws + WS_SWT + t * 4;
  #pragma unroll
  for (int d4 = 0; d4 < 16; ++d4) {
    const float4 s0 = *(const float4*)(sp + (d4 * 4 + 0) * NS);
    const float4 s1 = *(const float4*)(sp + (d4 * 4 + 1) * NS);
    const float4 s2 = *(const float4*)(sp + (d4 * 4 + 2) * NS);
    const float4 s3 = *(const float4*)(sp + (d4 * 4 + 3) * NS);
    #pragma unroll
    for (int r = 0; r < 8; ++r) {
      const float4 u4 = *(const float4*)(&u_lds[r * DIM + d4 * 4]);  // broadcast read
      acc[r][0] = fmaf(u4.w, s3.x, fmaf(u4.z, s2.x, fmaf(u4.y, s1.x, fmaf(u4.x, s0.x, acc[r][0]))));
      acc[r][1] = fmaf(u4.w, s3.y, fmaf(u4.z, s2.y, fmaf(u4.y, s1.y, fmaf(u4.x, s0.y, acc[r][1]))));
      acc[r][2] = fmaf(u4.w, s3.z, fmaf(u4.z, s2.z, fmaf(u4.y, s1.z, fmaf(u4.x, s0.z, acc[r][2]))));
      acc[r][3] = fmaf(u4.w, s3.w, fmaf(u4.z, s2.w, fmaf(u4.y, s1.w, fmaf(u4.x, s0.w, acc[r][3]))));
    }
  }

  int labv[8];
  #pragma unroll
  for (int r = 0; r < 8; ++r) labv[r] = label[r0 + r];

  const float4 sq = *(const float4*)(ws + WS_SLQ + t * 4);
  const int4  sid = *(const int4*)(sampled + t * 4);

  // per-thread online softmax over its 4 logits (hit-masked)
  float m[8], l[8];
  #pragma unroll
  for (int r = 0; r < 8; ++r) {
    float lg0 = acc[r][0] - sq.x; if (sid.x == labv[r]) lg0 -= 1e9f;
    float lg1 = acc[r][1] - sq.y; if (sid.y == labv[r]) lg1 -= 1e9f;
    float lg2 = acc[r][2] - sq.z; if (sid.z == labv[r]) lg2 -= 1e9f;
    float lg3 = acc[r][3] - sq.w; if (sid.w == labv[r]) lg3 -= 1e9f;
    float mm = fmaxf(fmaxf(lg0, lg1), fmaxf(lg2, lg3));
    l[r] = __expf(lg0 - mm) + __expf(lg1 - mm) + __expf(lg2 - mm) + __expf(lg3 - mm);
    m[r] = mm;
  }

  // 64-lane butterfly combine (all lanes of a wave hold the same 8 rows)
  #pragma unroll
  for (int off = 1; off < 64; off <<= 1) {
    #pragma unroll
    for (int r = 0; r < 8; ++r) {
      float om = __shfl_xor(m[r], off, 64);
      float ol = __shfl_xor(l[r], off, 64);
      float nm = fmaxf(m[r], om);
      l[r] = l[r] * __expf(m[r] - nm) + ol * __expf(om - nm);
      m[r] = nm;
    }
  }

  const int wave = t >> 6;
  if ((t & 63) == 0) {
    #pragma unroll
    for (int r = 0; r < 8; ++r) { red_m[wave][r] = m[r]; red_l[wave][r] = l[r]; }
  }
  __syncthreads();

  if (t < 8) {
    const int r = t;
    float mm = red_m[0][r], ll = red_l[0][r];
    #pragma unroll
    for (int w = 1; w < 4; ++w) {
      float om = red_m[w][r], ol = red_l[w][r];
      float nm = fmaxf(mm, om);
      ll = ll * __expf(mm - nm) + ol * __expf(om - nm);
      mm = nm;
    }
    // loss = logsumexp(true_logit, sampled...) - true_logit
    const float tl = ws[WS_TLOG + r0 + r];
    const float M = fmaxf(mm, tl);
    const float loss = logf(ll * __expf(mm - M) + __expf(tl - M)) + (M - tl);
    out[r0 + r] = loss;
  }
}

extern "C" void kernel_launch(void* const* d_in, const int* in_sizes, int n_in,
                              void* d_out, int out_size, void* d_ws, size_t ws_size,
                              hipStream_t stream) {
  const float* item  = (const float*)d_in[0];
  const float* user  = (const float*)d_in[1];
  const int* label   = (const int*)d_in[2];
  const int* sampled = (const int*)d_in[3];
  float* ws = (float*)d_ws;
  float* out = (float*)d_out;

  prep_kernel<<<NS + BATCH, 64, 0, stream>>>(item, user, label, sampled, ws);
  main_kernel<<<BATCH / 8, 256, 0, stream>>>(label, sampled, user, ws, out);
}